// Round 1
// 244.780 us; speedup vs baseline: 1.0154x; 1.0154x over previous
//
#include <hip/hip_runtime.h>
#include <hip/hip_fp16.h>
#include <math.h>

#define SCAN_CHUNK 2048
#define NBLK 256          // bucket-pass blocks (pass A/B edge slicing)
#define BSH 9             // bucket = dst >> 9 (512 nodes per bucket)
#define BNODES 512

// NodeInfo int2: .x = row start (rs), .y = dinv bits
// bucketed record int2: {src | (dst&511)<<17, ew bits}; csr record: {src, ew bits}
// h1 is stored PRE-SCALED by dinv[row] (done in kC); h2 likewise (done in agg1).

// ---------------- pass A: bucket-count (LDS atomics) || gemm1 part 1 ----------------

__global__ __launch_bounds__(256) void kA(const int* __restrict__ dst, int e,
                                          int* __restrict__ hist, int nbuck,
                                          const float* __restrict__ x,
                                          const float* __restrict__ W,
                                          __half* __restrict__ h1, int n,
                                          int nbB, int nbG, int gbase) {
    __shared__ float xs[32][128];  // 16 KB (gemm role)
    int bid = blockIdx.x;
    long long T = nbB + nbG;
    long long g = ((long long)bid * nbG) / T;
    bool is_g = (((long long)(bid + 1) * nbG) / T) > g;
    int t = threadIdx.x;

    if (!is_g) {
        __shared__ int cnt[512];
        int eb = bid - (int)g;
        for (int j = t; j < nbuck; j += 256) cnt[j] = 0;
        __syncthreads();
        long long e0 = (long long)eb * e / NBLK;
        long long e1 = (long long)(eb + 1) * e / NBLK;
        for (long long i = e0 + t; i < e1; i += 256)
            atomicAdd(&cnt[dst[i] >> BSH], 1);
        __syncthreads();
        for (int j = t; j < nbuck; j += 256)
            hist[(size_t)j * NBLK + eb] = cnt[j];
        return;
    }

    // ---- gemm1 block: rows [(gbase+g)*32 ...) ----
    int row0 = (gbase + (int)g) * 32;
#pragma unroll
    for (int it = 0; it < 4; ++it) {
        int idx = (it * 256 + t) * 4;
        int r = idx >> 7, k = idx & 127;
        int gr = row0 + r;
        float4 v = (gr < n) ? *(const float4*)(x + (size_t)gr * 128 + k)
                            : make_float4(0.f, 0.f, 0.f, 0.f);
        *(float4*)&xs[r][k] = v;
    }
    __syncthreads();
    int tc = t & 31, tr = t >> 5;
    int c0 = tc * 4;
    float4 acc[4];
#pragma unroll
    for (int j = 0; j < 4; ++j) acc[j] = make_float4(0.f, 0.f, 0.f, 0.f);
    for (int k = 0; k < 128; k += 4) {
        float4 wv0 = *(const float4*)(W + (size_t)(k + 0) * 128 + c0);
        float4 wv1 = *(const float4*)(W + (size_t)(k + 1) * 128 + c0);
        float4 wv2 = *(const float4*)(W + (size_t)(k + 2) * 128 + c0);
        float4 wv3 = *(const float4*)(W + (size_t)(k + 3) * 128 + c0);
#pragma unroll
        for (int j = 0; j < 4; ++j) {
            float4 xv = *(const float4*)&xs[tr + 8 * j][k];
            acc[j].x += xv.x * wv0.x + xv.y * wv1.x + xv.z * wv2.x + xv.w * wv3.x;
            acc[j].y += xv.x * wv0.y + xv.y * wv1.y + xv.z * wv2.y + xv.w * wv3.y;
            acc[j].z += xv.x * wv0.z + xv.y * wv1.z + xv.z * wv2.z + xv.w * wv3.z;
            acc[j].w += xv.x * wv0.w + xv.y * wv1.w + xv.z * wv2.w + xv.w * wv3.w;
        }
    }
#pragma unroll
    for (int j = 0; j < 4; ++j) {
        int gr = row0 + tr + 8 * j;
        if (gr < n) {
            union { __half2 h[2]; uint2 u; } pk;
            pk.h[0] = __floats2half2_rn(acc[j].x, acc[j].y);
            pk.h[1] = __floats2half2_rn(acc[j].z, acc[j].w);
            *(uint2*)(h1 + (size_t)gr * 128 + c0) = pk.u;
        }
    }
}

// ---------------- scan over hist (nh ints), in-place, 2-level ----------------

__global__ __launch_bounds__(256) void k_scanh(int* __restrict__ hist,
                                               int* __restrict__ bsum, int nh) {
    __shared__ int sh[256];
    int b = blockIdx.x, t = threadIdx.x;
    int base = b * SCAN_CHUNK + t * 8;
    int v[8];
    int s = 0;
#pragma unroll
    for (int j = 0; j < 8; ++j) {
        int i = base + j;
        v[j] = (i < nh) ? hist[i] : 0;
        s += v[j];
    }
    sh[t] = s;
    __syncthreads();
    for (int off = 1; off < 256; off <<= 1) {
        int u = (t >= off) ? sh[t - off] : 0;
        __syncthreads();
        sh[t] += u;
        __syncthreads();
    }
    int excl = (t > 0) ? sh[t - 1] : 0;
    if (t == 255) bsum[b] = sh[255];
    int run = excl;
#pragma unroll
    for (int j = 0; j < 8; ++j) {
        int i = base + j;
        if (i < nh) hist[i] = run;
        run += v[j];
    }
}

__global__ void k_scan2(const int* __restrict__ bsum, int* __restrict__ boff, int nb) {
    int t = threadIdx.x;  // one wave
    int v = (t < nb) ? bsum[t] : 0;
    for (int off = 1; off < 64; off <<= 1) {
        int u = __shfl_up(v, off, 64);
        if (t >= off) v += u;
    }
    int e = __shfl_up(v, 1, 64);
    if (t == 0) e = 0;
    if (t < nb) boff[t] = e;
}

// ---------------- pass B: bucket-scatter (LDS ranks) || gemm1 part 2 ----------------

__global__ __launch_bounds__(256) void kB(const int* __restrict__ src,
                                          const int* __restrict__ dst,
                                          const float* __restrict__ ew, int e,
                                          const int* __restrict__ hist,
                                          const int* __restrict__ boff, int nbuck,
                                          int2* __restrict__ bucketed,
                                          const float* __restrict__ x,
                                          const float* __restrict__ W,
                                          __half* __restrict__ h1, int n,
                                          int nbB, int nbG, int gbase) {
    __shared__ float xs[32][128];
    int bid = blockIdx.x;
    long long T = nbB + nbG;
    long long g = ((long long)bid * nbG) / T;
    bool is_g = (((long long)(bid + 1) * nbG) / T) > g;
    int t = threadIdx.x;

    if (!is_g) {
        __shared__ int wc[512];
        int eb = bid - (int)g;
        for (int j = t; j < nbuck; j += 256) {
            int idx = j * NBLK + eb;
            wc[j] = hist[idx] + boff[idx >> 11];
        }
        __syncthreads();
        long long e0 = (long long)eb * e / NBLK;
        long long e1 = (long long)(eb + 1) * e / NBLK;
        for (long long i = e0 + t; i < e1; i += 256) {
            int d = dst[i];
            int b = d >> BSH;
            int pos = atomicAdd(&wc[b], 1);
            int2 rec;
            rec.x = src[i] | ((d & (BNODES - 1)) << 17);
            rec.y = __float_as_int(ew[i]);
            bucketed[pos] = rec;
        }
        return;
    }

    int row0 = (gbase + (int)g) * 32;
#pragma unroll
    for (int it = 0; it < 4; ++it) {
        int idx = (it * 256 + t) * 4;
        int r = idx >> 7, k = idx & 127;
        int gr = row0 + r;
        float4 v = (gr < n) ? *(const float4*)(x + (size_t)gr * 128 + k)
                            : make_float4(0.f, 0.f, 0.f, 0.f);
        *(float4*)&xs[r][k] = v;
    }
    __syncthreads();
    int tc = t & 31, tr = t >> 5;
    int c0 = tc * 4;
    float4 acc[4];
#pragma unroll
    for (int j = 0; j < 4; ++j) acc[j] = make_float4(0.f, 0.f, 0.f, 0.f);
    for (int k = 0; k < 128; k += 4) {
        float4 wv0 = *(const float4*)(W + (size_t)(k + 0) * 128 + c0);
        float4 wv1 = *(const float4*)(W + (size_t)(k + 1) * 128 + c0);
        float4 wv2 = *(const float4*)(W + (size_t)(k + 2) * 128 + c0);
        float4 wv3 = *(const float4*)(W + (size_t)(k + 3) * 128 + c0);
#pragma unroll
        for (int j = 0; j < 4; ++j) {
            float4 xv = *(const float4*)&xs[tr + 8 * j][k];
            acc[j].x += xv.x * wv0.x + xv.y * wv1.x + xv.z * wv2.x + xv.w * wv3.x;
            acc[j].y += xv.x * wv0.y + xv.y * wv1.y + xv.z * wv2.y + xv.w * wv3.y;
            acc[j].z += xv.x * wv0.z + xv.y * wv1.z + xv.z * wv2.z + xv.w * wv3.z;
            acc[j].w += xv.x * wv0.w + xv.y * wv1.w + xv.z * wv2.w + xv.w * wv3.w;
        }
    }
#pragma unroll
    for (int j = 0; j < 4; ++j) {
        int gr = row0 + tr + 8 * j;
        if (gr < n) {
            union { __half2 h[2]; uint2 u; } pk;
            pk.h[0] = __floats2half2_rn(acc[j].x, acc[j].y);
            pk.h[1] = __floats2half2_rn(acc[j].z, acc[j].w);
            *(uint2*)(h1 + (size_t)gr * 128 + c0) = pk.u;
        }
    }
}

// ---------------- pass C: per-bucket deg/dinv/rs, final CSR (plain ew), h1 *= dinv ----------------

__global__ __launch_bounds__(256) void kC(const int2* __restrict__ bucketed,
                                          const int* __restrict__ hist,
                                          const int* __restrict__ boff,
                                          int nbuck, int n, int e,
                                          int2* __restrict__ csr,
                                          int2* __restrict__ nodeinfo,
                                          __half* __restrict__ h1) {
    __shared__ int   cnts[BNODES];
    __shared__ float degs[BNODES];
    __shared__ float dinvs[BNODES];
    __shared__ int   wcs[BNODES];
    __shared__ int   sh[256];
    int b = blockIdx.x, t = threadIdx.x;

    int i0 = b * NBLK;
    int bstart = hist[i0] + boff[i0 >> 11];
    int bend;
    if (b == nbuck - 1) bend = e;
    else {
        int i1 = (b + 1) * NBLK;
        bend = hist[i1] + boff[i1 >> 11];
    }

    cnts[t] = 0; cnts[t + 256] = 0;
    degs[t] = 0.f; degs[t + 256] = 0.f;
    __syncthreads();

    for (int i = bstart + t; i < bend; i += 256) {
        int2 rec = bucketed[i];
        int l = (rec.x >> 17) & (BNODES - 1);
        atomicAdd(&cnts[l], 1);
        atomicAdd(&degs[l], __int_as_float(rec.y));
    }
    __syncthreads();

    // scan 512 counts (2 per thread) -> local rs; dinv
    int c0 = cnts[2 * t], c1 = cnts[2 * t + 1];
    sh[t] = c0 + c1;
    __syncthreads();
    for (int off = 1; off < 256; off <<= 1) {
        int u = (t >= off) ? sh[t - off] : 0;
        __syncthreads();
        sh[t] += u;
        __syncthreads();
    }
    int excl = (t > 0) ? sh[t - 1] : 0;

    int rs0 = bstart + excl;
    int rs1 = rs0 + c0;
    wcs[2 * t] = rs0;
    wcs[2 * t + 1] = rs1;
#pragma unroll
    for (int q = 0; q < 2; ++q) {
        int l = 2 * t + q;
        float dv = 1.0f / sqrtf(1.0f + degs[l]);
        dinvs[l] = dv;
        int gnode = b * BNODES + l;
        if (gnode < n) {
            int2 ni;
            ni.x = (q == 0) ? rs0 : rs1;
            ni.y = __float_as_int(dv);
            nodeinfo[gnode] = ni;
        }
    }
    if (b == nbuck - 1 && t == 0) {
        int2 sent; sent.x = e; sent.y = 0;
        nodeinfo[n] = sent;
    }
    __syncthreads();

    // scatter into final CSR: {src, plain ew}
    for (int i = bstart + t; i < bend; i += 256) {
        int2 rec = bucketed[i];
        int l = (rec.x >> 17) & (BNODES - 1);
        int pos = atomicAdd(&wcs[l], 1);
        int2 o;
        o.x = rec.x & 0x1FFFF;
        o.y = rec.y;
        csr[pos] = o;
    }

    // scale this bucket's h1 rows by dinv (h1 complete after kB)
    int nrows = n - b * BNODES;
    if (nrows > BNODES) nrows = BNODES;
    uint4* h1v = (uint4*)h1;  // 16 uint4 per row
    for (int idx = t; idx < nrows * 16; idx += 256) {
        int row = idx >> 4, seg = idx & 15;
        float dv = dinvs[row];
        size_t off = ((size_t)(b * BNODES + row)) * 16 + seg;
        uint4 v = h1v[off];
        __half2* hp = (__half2*)&v;
#pragma unroll
        for (int k = 0; k < 4; ++k) {
            float2 f = __half22float2(hp[k]);
            hp[k] = __floats2half2_rn(dv * f.x, dv * f.y);
        }
        h1v[off] = v;
    }
}

// ---------------- layer 1 aggregation + relu + fused GEMM2 ----------------
// wave per node; 4 edge streams x 16 lanes; 16B loads.
// Software pipeline DEPTH 2 on the h1-row gather (csr 3 ahead, h1 2 ahead):
// each stream keeps 2 h1 gathers in flight -> 8 outstanding per wave,
// doubling memory-level parallelism vs the previous 1-deep pipeline.

__global__ __launch_bounds__(256) void k_agg1(const __half* __restrict__ h1,
                                              const int2* __restrict__ nodeinfo,
                                              const int2* __restrict__ csr,
                                              const float* __restrict__ b1,
                                              const float* __restrict__ W2g,
                                              __half* __restrict__ h2, int n) {
    __shared__ float a1s[4][128];
    __shared__ float wt[16][132];  // W2 transposed [c][k], padded
    __shared__ float dnl[4];
    int t = threadIdx.x;
#pragma unroll
    for (int it = 0; it < 8; ++it) {
        int idx = it * 256 + t;  // = k*16 + c
        wt[idx & 15][idx >> 4] = W2g[idx];
    }
    int wv = t >> 6;
    int lane = t & 63;
    int grp = lane >> 4;   // edge stream 0..3
    int sl = lane & 15;    // feature slot: feats [8*sl, 8*sl+8)
    int i = blockIdx.x * 4 + wv;
    float acc[8];
#pragma unroll
    for (int k = 0; k < 8; ++k) acc[k] = 0.f;
    float di = 0.f;
    if (i < n) {
        int2 ni = nodeinfo[i];
        int begin = ni.x;
        int end = ((const int*)nodeinfo)[(size_t)(i + 1) * 2];
        di = __int_as_float(ni.y);
        if (lane == 0) dnl[wv] = di;
        if (grp == 0) {  // self term: h1s[i] (pre-scaled), weight 1
            uint4 sv = *((const uint4*)(h1 + (size_t)i * 128) + sl);
            const __half2* hp = (const __half2*)&sv;
#pragma unroll
            for (int k = 0; k < 4; ++k) {
                float2 f = __half22float2(hp[k]);
                acc[2 * k] = f.x; acc[2 * k + 1] = f.y;
            }
        }
        int len = end - begin;
        int m = (len + 3) >> 2;
        if (m > 0) {
            // depth-2 pipeline: csr 3 ahead, h1 rows 2 ahead
            int j0 = begin + grp;
            bool v0 = j0 < end;
            int2 er0 = csr[v0 ? j0 : begin];
            float w0 = v0 ? __int_as_float(er0.y) : 0.f;
            uint4 hv0 = *((const uint4*)(h1 + (size_t)er0.x * 128) + sl);
            int j1 = j0 + 4;
            bool v1 = j1 < end;
            int2 er1 = csr[v1 ? j1 : begin];
            float w1 = v1 ? __int_as_float(er1.y) : 0.f;
            uint4 hv1 = *((const uint4*)(h1 + (size_t)er1.x * 128) + sl);
            int j2 = j1 + 4;
            bool v2 = j2 < end;
            int2 er2 = csr[v2 ? j2 : begin];
            float w2 = v2 ? __int_as_float(er2.y) : 0.f;
#pragma unroll 2
            for (int it2 = 2; it2 < m; ++it2) {
                uint4 hv2 = *((const uint4*)(h1 + (size_t)er2.x * 128) + sl);
                int j3 = j2 + 4;
                bool v3 = j3 < end;
                int2 er3 = csr[v3 ? j3 : begin];
                float w3 = v3 ? __int_as_float(er3.y) : 0.f;
                const __half2* hp = (const __half2*)&hv0;
#pragma unroll
                for (int k = 0; k < 4; ++k) {
                    float2 f = __half22float2(hp[k]);
                    acc[2 * k]     += w0 * f.x;
                    acc[2 * k + 1] += w0 * f.y;
                }
                hv0 = hv1; w0 = w1;
                hv1 = hv2; w1 = w2;
                er2 = er3; w2 = w3; j2 = j3;
            }
            {   // epilogue: drain the two in-flight rows (w's are zero-masked
                // for invalid slots, so this is safe for m == 1 and m == 2)
                const __half2* hp = (const __half2*)&hv0;
#pragma unroll
                for (int k = 0; k < 4; ++k) {
                    float2 f = __half22float2(hp[k]);
                    acc[2 * k]     += w0 * f.x;
                    acc[2 * k + 1] += w0 * f.y;
                }
                const __half2* hq = (const __half2*)&hv1;
#pragma unroll
                for (int k = 0; k < 4; ++k) {
                    float2 f = __half22float2(hq[k]);
                    acc[2 * k]     += w1 * f.x;
                    acc[2 * k + 1] += w1 * f.y;
                }
            }
        }
    }
    // combine the 4 edge streams
#pragma unroll
    for (int k = 0; k < 8; ++k) {
        acc[k] += __shfl_xor(acc[k], 16, 64);
        acc[k] += __shfl_xor(acc[k], 32, 64);
    }
    if (i < n && grp == 0) {
#pragma unroll
        for (int k = 0; k < 8; ++k)
            a1s[wv][8 * sl + k] = fmaxf(di * acc[k] + b1[8 * sl + k], 0.f);
    }
    __syncthreads();
    // fused gemm2; write h2s = dinv * (a1 @ W2)
    int oi = t >> 2, q = t & 3;
    int node = oi >> 4, c = oi & 15;
    const float* arow = a1s[node];
    float accd = 0.f;
#pragma unroll
    for (int j = 0; j < 32; ++j) accd += arow[q + 4 * j] * wt[c][q + 4 * j];
    accd += __shfl_xor(accd, 1, 64);
    accd += __shfl_xor(accd, 2, 64);
    int gi = blockIdx.x * 4 + node;
    if (q == 0 && gi < n) h2[(size_t)gi * 16 + c] = __float2half(dnl[node] * accd);
}

// ---------------- layer 2 aggregation + bias + softmax ----------------
// 4 edges per iteration: the 4 h2 gathers issue together (4-way MLP/thread).

__global__ __launch_bounds__(256) void k_agg2(const __half* __restrict__ h2,
                                              const int2* __restrict__ nodeinfo,
                                              const int2* __restrict__ csr,
                                              const float* __restrict__ b2,
                                              float* __restrict__ out, int n) {
    int t = blockIdx.x * 256 + threadIdx.x;
    int i = t >> 4;
    int c = t & 15;
    if (i >= n) return;
    int2 ni = nodeinfo[i];
    int begin = ni.x;
    int end = ((const int*)nodeinfo)[(size_t)(i + 1) * 2];
    float di = __int_as_float(ni.y);
    float acc = __half2float(h2[(size_t)i * 16 + c]);  // self (h2 pre-scaled)
    int j = begin;
    for (; j + 4 <= end; j += 4) {
        int2 e0 = csr[j], e1 = csr[j + 1], e2 = csr[j + 2], e3 = csr[j + 3];
        float f0 = __half2float(h2[(size_t)e0.x * 16 + c]);
        float f1 = __half2float(h2[(size_t)e1.x * 16 + c]);
        float f2 = __half2float(h2[(size_t)e2.x * 16 + c]);
        float f3 = __half2float(h2[(size_t)e3.x * 16 + c]);
        acc += __int_as_float(e0.y) * f0;
        acc += __int_as_float(e1.y) * f1;
        acc += __int_as_float(e2.y) * f2;
        acc += __int_as_float(e3.y) * f3;
    }
    for (; j < end; ++j) {
        int2 e0 = csr[j];
        acc += __int_as_float(e0.y) * __half2float(h2[(size_t)e0.x * 16 + c]);
    }
    acc = di * acc + b2[c];
    float m = acc;
    for (int off = 8; off; off >>= 1) m = fmaxf(m, __shfl_xor(m, off, 16));
    float ex = expf(acc - m);
    float ssum = ex;
    for (int off = 8; off; off >>= 1) ssum += __shfl_xor(ssum, off, 16);
    out[(size_t)i * 16 + c] = ex / ssum;
}

// ---------------- launch ----------------

extern "C" void kernel_launch(void* const* d_in, const int* in_sizes, int n_in,
                              void* d_out, int out_size, void* d_ws, size_t ws_size,
                              hipStream_t stream) {
    const float* x  = (const float*)d_in[0];
    const int*   ei = (const int*)d_in[1];
    const float* ew = (const float*)d_in[2];
    const float* W1 = (const float*)d_in[3];
    const float* b1 = (const float*)d_in[4];
    const float* W2 = (const float*)d_in[5];
    const float* b2 = (const float*)d_in[6];
    float* out = (float*)d_out;

    const int N = in_sizes[0] / 128;
    const int E = in_sizes[2];
    const int* src = ei;
    const int* dst = ei + E;

    const int nbuck = (N + BNODES - 1) >> BSH;           // 196
    const int nh = nbuck * NBLK;                          // 50176
    const int nbS = (nh + SCAN_CHUNK - 1) / SCAN_CHUNK;   // 25

    char* w = (char*)d_ws;
    int2*   bucketed = (int2*)w;              w += (size_t)E * 8;
    int2*   csr      = (int2*)w;              w += (size_t)E * 8;
    __half* h1       = (__half*)w;            w += (size_t)N * 128 * 2;
    __half* h2       = (__half*)w;            w += (size_t)N * 16 * 2;
    int2*   nodeinfo = (int2*)w;              w += (size_t)(N + 1) * 8;
    int*    hist     = (int*)w;               w += (size_t)nh * 4;
    int*    bsum     = (int*)w;               w += 64 * 4;
    int*    boff     = (int*)w;               w += 64 * 4;

    int nbG_total = (N + 31) / 32;           // 3125 gemm blocks
    int nbG1 = nbG_total / 2;
    int nbG2 = nbG_total - nbG1;

    kA<<<NBLK + nbG1, 256, 0, stream>>>(dst, E, hist, nbuck, x, W1, h1, N,
                                        NBLK, nbG1, 0);
    k_scanh<<<nbS, 256, 0, stream>>>(hist, bsum, nh);
    k_scan2<<<1, 64, 0, stream>>>(bsum, boff, nbS);
    kB<<<NBLK + nbG2, 256, 0, stream>>>(src, dst, ew, E, hist, boff, nbuck,
                                        bucketed, x, W1, h1, N, NBLK, nbG2, nbG1);
    kC<<<nbuck, 256, 0, stream>>>(bucketed, hist, boff, nbuck, N, E,
                                  csr, nodeinfo, h1);
    k_agg1<<<(N + 3) / 4, 256, 0, stream>>>(h1, nodeinfo, csr, b1, W2, h2, N);
    k_agg2<<<(N + 15) / 16, 256, 0, stream>>>(h2, nodeinfo, csr, b2, out, N);
}

// Round 2
// 222.958 us; speedup vs baseline: 1.1148x; 1.0979x over previous
//
#include <hip/hip_runtime.h>
#include <hip/hip_fp16.h>
#include <math.h>

#define SCAN_CHUNK 2048
#define NBLK 256          // bucket-pass blocks (pass A/B edge slicing)
#define BSH 9             // bucket = dst >> 9 (512 nodes per bucket)
#define BNODES 512

// NodeInfo int2: .x = row start (rs), .y = dinv bits
// bucketed record int2: {src | (dst&511)<<17, ew bits}; csr record: {src, ew bits}
// h1 is stored PRE-SCALED by dinv[row] (done in kC); h2 likewise (done in agg1).

typedef __attribute__((ext_vector_type(8))) _Float16 f16x8;
typedef __attribute__((ext_vector_type(16))) float f32x16;

// ---- gemm1 via MFMA: one block computes rows [row0, row0+32) x all 128 cols ----
// wave wv handles cols [wv*32, wv*32+32). K = 128 in 8 steps of 16.
// A-frag (32x32x16_f16): lane l -> row = l&31, k = (l>>5)*8 + j (8 contig halves)
// B-frag:                 lane l -> col = l&31, k = (l>>5)*8 + j
// C/D:                    col = lane&31, row = (r&3) + 8*(r>>2) + 4*(lane>>5)
__device__ __forceinline__ void gemm1_mfma(const float* __restrict__ x,
                                           const float* __restrict__ W,
                                           __half* __restrict__ h1, int n,
                                           int row0, int t) {
    int wv = t >> 6, lane = t & 63;
    int m = lane & 31, kh = lane >> 5;
    int col0 = wv * 32;

    f16x8 a[8], b[8];
    int gr = row0 + m;
    bool rv = gr < n;
    const float* xr = x + (size_t)(rv ? gr : 0) * 128 + kh * 8;
#pragma unroll
    for (int ks = 0; ks < 8; ++ks) {
        float4 u0, u1;
        if (rv) {
            u0 = *(const float4*)(xr + ks * 16);
            u1 = *(const float4*)(xr + ks * 16 + 4);
        } else {
            u0 = make_float4(0.f, 0.f, 0.f, 0.f);
            u1 = u0;
        }
        a[ks][0] = (_Float16)u0.x; a[ks][1] = (_Float16)u0.y;
        a[ks][2] = (_Float16)u0.z; a[ks][3] = (_Float16)u0.w;
        a[ks][4] = (_Float16)u1.x; a[ks][5] = (_Float16)u1.y;
        a[ks][6] = (_Float16)u1.z; a[ks][7] = (_Float16)u1.w;
    }
    const float* wp = W + col0 + m + (size_t)kh * 8 * 128;
#pragma unroll
    for (int ks = 0; ks < 8; ++ks) {
#pragma unroll
        for (int j = 0; j < 8; ++j)
            b[ks][j] = (_Float16)wp[(size_t)(ks * 16 + j) * 128];
    }
    f32x16 acc;
#pragma unroll
    for (int r = 0; r < 16; ++r) acc[r] = 0.f;
#pragma unroll
    for (int ks = 0; ks < 8; ++ks)
        acc = __builtin_amdgcn_mfma_f32_32x32x16_f16(a[ks], b[ks], acc, 0, 0, 0);
#pragma unroll
    for (int r = 0; r < 16; ++r) {
        int row = (r & 3) + 8 * (r >> 2) + 4 * kh;
        int g = row0 + row;
        if (g < n) h1[(size_t)g * 128 + col0 + m] = __float2half(acc[r]);
    }
}

// ---------------- pass A: bucket-count (LDS atomics) || gemm1 part 1 ----------------

__global__ __launch_bounds__(256) void kA(const int* __restrict__ dst, int e,
                                          int* __restrict__ hist, int nbuck,
                                          const float* __restrict__ x,
                                          const float* __restrict__ W,
                                          __half* __restrict__ h1, int n,
                                          int nbB, int nbG, int gbase) {
    int bid = blockIdx.x;
    long long T = nbB + nbG;
    long long g = ((long long)bid * nbG) / T;
    bool is_g = (((long long)(bid + 1) * nbG) / T) > g;
    int t = threadIdx.x;

    if (!is_g) {
        __shared__ int cnt[512];
        int eb = bid - (int)g;
        for (int j = t; j < nbuck; j += 256) cnt[j] = 0;
        __syncthreads();
        long long e0 = (long long)eb * e / NBLK;
        long long e1 = (long long)(eb + 1) * e / NBLK;
        for (long long i = e0 + t; i < e1; i += 256)
            atomicAdd(&cnt[dst[i] >> BSH], 1);
        __syncthreads();
        for (int j = t; j < nbuck; j += 256)
            hist[(size_t)j * NBLK + eb] = cnt[j];
        return;
    }

    gemm1_mfma(x, W, h1, n, (gbase + (int)g) * 32, t);
}

// ---------------- scan over hist (nh ints), in-place, 2-level ----------------

__global__ __launch_bounds__(256) void k_scanh(int* __restrict__ hist,
                                               int* __restrict__ bsum, int nh) {
    __shared__ int sh[256];
    int b = blockIdx.x, t = threadIdx.x;
    int base = b * SCAN_CHUNK + t * 8;
    int v[8];
    int s = 0;
#pragma unroll
    for (int j = 0; j < 8; ++j) {
        int i = base + j;
        v[j] = (i < nh) ? hist[i] : 0;
        s += v[j];
    }
    sh[t] = s;
    __syncthreads();
    for (int off = 1; off < 256; off <<= 1) {
        int u = (t >= off) ? sh[t - off] : 0;
        __syncthreads();
        sh[t] += u;
        __syncthreads();
    }
    int excl = (t > 0) ? sh[t - 1] : 0;
    if (t == 255) bsum[b] = sh[255];
    int run = excl;
#pragma unroll
    for (int j = 0; j < 8; ++j) {
        int i = base + j;
        if (i < nh) hist[i] = run;
        run += v[j];
    }
}

__global__ void k_scan2(const int* __restrict__ bsum, int* __restrict__ boff, int nb) {
    int t = threadIdx.x;  // one wave
    int v = (t < nb) ? bsum[t] : 0;
    for (int off = 1; off < 64; off <<= 1) {
        int u = __shfl_up(v, off, 64);
        if (t >= off) v += u;
    }
    int e = __shfl_up(v, 1, 64);
    if (t == 0) e = 0;
    if (t < nb) boff[t] = e;
}

// ---------------- pass B: bucket-scatter (LDS ranks) || gemm1 part 2 ----------------

__global__ __launch_bounds__(256) void kB(const int* __restrict__ src,
                                          const int* __restrict__ dst,
                                          const float* __restrict__ ew, int e,
                                          const int* __restrict__ hist,
                                          const int* __restrict__ boff, int nbuck,
                                          int2* __restrict__ bucketed,
                                          const float* __restrict__ x,
                                          const float* __restrict__ W,
                                          __half* __restrict__ h1, int n,
                                          int nbB, int nbG, int gbase) {
    int bid = blockIdx.x;
    long long T = nbB + nbG;
    long long g = ((long long)bid * nbG) / T;
    bool is_g = (((long long)(bid + 1) * nbG) / T) > g;
    int t = threadIdx.x;

    if (!is_g) {
        __shared__ int wc[512];
        int eb = bid - (int)g;
        for (int j = t; j < nbuck; j += 256) {
            int idx = j * NBLK + eb;
            wc[j] = hist[idx] + boff[idx >> 11];
        }
        __syncthreads();
        long long e0 = (long long)eb * e / NBLK;
        long long e1 = (long long)(eb + 1) * e / NBLK;
        for (long long i = e0 + t; i < e1; i += 256) {
            int d = dst[i];
            int b = d >> BSH;
            int pos = atomicAdd(&wc[b], 1);
            int2 rec;
            rec.x = src[i] | ((d & (BNODES - 1)) << 17);
            rec.y = __float_as_int(ew[i]);
            bucketed[pos] = rec;
        }
        return;
    }

    gemm1_mfma(x, W, h1, n, (gbase + (int)g) * 32, t);
}

// ---------------- pass C: per-bucket deg/dinv/rs, final CSR (plain ew), h1 *= dinv ----------------

__global__ __launch_bounds__(256) void kC(const int2* __restrict__ bucketed,
                                          const int* __restrict__ hist,
                                          const int* __restrict__ boff,
                                          int nbuck, int n, int e,
                                          int2* __restrict__ csr,
                                          int2* __restrict__ nodeinfo,
                                          __half* __restrict__ h1) {
    __shared__ int   cnts[BNODES];
    __shared__ float degs[BNODES];
    __shared__ float dinvs[BNODES];
    __shared__ int   wcs[BNODES];
    __shared__ int   sh[256];
    int b = blockIdx.x, t = threadIdx.x;

    int i0 = b * NBLK;
    int bstart = hist[i0] + boff[i0 >> 11];
    int bend;
    if (b == nbuck - 1) bend = e;
    else {
        int i1 = (b + 1) * NBLK;
        bend = hist[i1] + boff[i1 >> 11];
    }

    cnts[t] = 0; cnts[t + 256] = 0;
    degs[t] = 0.f; degs[t + 256] = 0.f;
    __syncthreads();

    for (int i = bstart + t; i < bend; i += 256) {
        int2 rec = bucketed[i];
        int l = (rec.x >> 17) & (BNODES - 1);
        atomicAdd(&cnts[l], 1);
        atomicAdd(&degs[l], __int_as_float(rec.y));
    }
    __syncthreads();

    // scan 512 counts (2 per thread) -> local rs; dinv
    int c0 = cnts[2 * t], c1 = cnts[2 * t + 1];
    sh[t] = c0 + c1;
    __syncthreads();
    for (int off = 1; off < 256; off <<= 1) {
        int u = (t >= off) ? sh[t - off] : 0;
        __syncthreads();
        sh[t] += u;
        __syncthreads();
    }
    int excl = (t > 0) ? sh[t - 1] : 0;

    int rs0 = bstart + excl;
    int rs1 = rs0 + c0;
    wcs[2 * t] = rs0;
    wcs[2 * t + 1] = rs1;
#pragma unroll
    for (int q = 0; q < 2; ++q) {
        int l = 2 * t + q;
        float dv = 1.0f / sqrtf(1.0f + degs[l]);
        dinvs[l] = dv;
        int gnode = b * BNODES + l;
        if (gnode < n) {
            int2 ni;
            ni.x = (q == 0) ? rs0 : rs1;
            ni.y = __float_as_int(dv);
            nodeinfo[gnode] = ni;
        }
    }
    if (b == nbuck - 1 && t == 0) {
        int2 sent; sent.x = e; sent.y = 0;
        nodeinfo[n] = sent;
    }
    __syncthreads();

    // scatter into final CSR: {src, plain ew}
    for (int i = bstart + t; i < bend; i += 256) {
        int2 rec = bucketed[i];
        int l = (rec.x >> 17) & (BNODES - 1);
        int pos = atomicAdd(&wcs[l], 1);
        int2 o;
        o.x = rec.x & 0x1FFFF;
        o.y = rec.y;
        csr[pos] = o;
    }

    // scale this bucket's h1 rows by dinv (h1 complete after kB)
    int nrows = n - b * BNODES;
    if (nrows > BNODES) nrows = BNODES;
    uint4* h1v = (uint4*)h1;  // 16 uint4 per row
    for (int idx = t; idx < nrows * 16; idx += 256) {
        int row = idx >> 4, seg = idx & 15;
        float dv = dinvs[row];
        size_t off = ((size_t)(b * BNODES + row)) * 16 + seg;
        uint4 v = h1v[off];
        __half2* hp = (__half2*)&v;
#pragma unroll
        for (int k = 0; k < 4; ++k) {
            float2 f = __half22float2(hp[k]);
            hp[k] = __floats2half2_rn(dv * f.x, dv * f.y);
        }
        h1v[off] = v;
    }
}

// ---------------- layer 1 aggregation + relu + fused GEMM2 ----------------
// wave per node; 4 edge streams x 16 lanes; 16B loads; software-pipelined (depth 1).

__global__ __launch_bounds__(256) void k_agg1(const __half* __restrict__ h1,
                                              const int2* __restrict__ nodeinfo,
                                              const int2* __restrict__ csr,
                                              const float* __restrict__ b1,
                                              const float* __restrict__ W2g,
                                              __half* __restrict__ h2, int n) {
    __shared__ float a1s[4][128];
    __shared__ float wt[16][132];  // W2 transposed [c][k], padded
    __shared__ float dnl[4];
    int t = threadIdx.x;
#pragma unroll
    for (int it = 0; it < 8; ++it) {
        int idx = it * 256 + t;  // = k*16 + c
        wt[idx & 15][idx >> 4] = W2g[idx];
    }
    int wv = t >> 6;
    int lane = t & 63;
    int grp = lane >> 4;   // edge stream 0..3
    int sl = lane & 15;    // feature slot: feats [8*sl, 8*sl+8)
    int i = blockIdx.x * 4 + wv;
    float acc[8];
#pragma unroll
    for (int k = 0; k < 8; ++k) acc[k] = 0.f;
    float di = 0.f;
    if (i < n) {
        int2 ni = nodeinfo[i];
        int begin = ni.x;
        int end = ((const int*)nodeinfo)[(size_t)(i + 1) * 2];
        di = __int_as_float(ni.y);
        if (lane == 0) dnl[wv] = di;
        if (grp == 0) {  // self term: h1s[i] (pre-scaled), weight 1
            uint4 sv = *((const uint4*)(h1 + (size_t)i * 128) + sl);
            const __half2* hp = (const __half2*)&sv;
#pragma unroll
            for (int k = 0; k < 4; ++k) {
                float2 f = __half22float2(hp[k]);
                acc[2 * k] = f.x; acc[2 * k + 1] = f.y;
            }
        }
        int len = end - begin;
        int m = (len + 3) >> 2;
        if (m > 0) {
            // pipeline: csr 2 ahead, h1 row 1 ahead
            int j0 = begin + grp;
            bool v0 = j0 < end;
            int2 er0 = csr[v0 ? j0 : begin];
            float w0 = v0 ? __int_as_float(er0.y) : 0.f;
            uint4 hv0 = *((const uint4*)(h1 + (size_t)er0.x * 128) + sl);
            int j1 = j0 + 4;
            bool v1 = j1 < end;
            int2 er1 = csr[v1 ? j1 : begin];
            float w1 = v1 ? __int_as_float(er1.y) : 0.f;
            for (int it2 = 1; it2 < m; ++it2) {
                uint4 hv1 = *((const uint4*)(h1 + (size_t)er1.x * 128) + sl);
                int j2 = j1 + 4;
                bool v2 = j2 < end;
                int2 er2 = csr[v2 ? j2 : begin];
                float w2 = v2 ? __int_as_float(er2.y) : 0.f;
                const __half2* hp = (const __half2*)&hv0;
#pragma unroll
                for (int k = 0; k < 4; ++k) {
                    float2 f = __half22float2(hp[k]);
                    acc[2 * k]     += w0 * f.x;
                    acc[2 * k + 1] += w0 * f.y;
                }
                hv0 = hv1; w0 = w1;
                er1 = er2; w1 = w2; j1 = j2;
            }
            const __half2* hp = (const __half2*)&hv0;
#pragma unroll
            for (int k = 0; k < 4; ++k) {
                float2 f = __half22float2(hp[k]);
                acc[2 * k]     += w0 * f.x;
                acc[2 * k + 1] += w0 * f.y;
            }
        }
    }
    // combine the 4 edge streams
#pragma unroll
    for (int k = 0; k < 8; ++k) {
        acc[k] += __shfl_xor(acc[k], 16, 64);
        acc[k] += __shfl_xor(acc[k], 32, 64);
    }
    if (i < n && grp == 0) {
#pragma unroll
        for (int k = 0; k < 8; ++k)
            a1s[wv][8 * sl + k] = fmaxf(di * acc[k] + b1[8 * sl + k], 0.f);
    }
    __syncthreads();
    // fused gemm2; write h2s = dinv * (a1 @ W2)
    int oi = t >> 2, q = t & 3;
    int node = oi >> 4, c = oi & 15;
    const float* arow = a1s[node];
    float accd = 0.f;
#pragma unroll
    for (int j = 0; j < 32; ++j) accd += arow[q + 4 * j] * wt[c][q + 4 * j];
    accd += __shfl_xor(accd, 1, 64);
    accd += __shfl_xor(accd, 2, 64);
    int gi = blockIdx.x * 4 + node;
    if (q == 0 && gi < n) h2[(size_t)gi * 16 + c] = __float2half(dnl[node] * accd);
}

// ---------------- layer 2 aggregation + bias + softmax ----------------
// 4 edges per iteration: the 4 h2 gathers issue together (4-way MLP/thread).

__global__ __launch_bounds__(256) void k_agg2(const __half* __restrict__ h2,
                                              const int2* __restrict__ nodeinfo,
                                              const int2* __restrict__ csr,
                                              const float* __restrict__ b2,
                                              float* __restrict__ out, int n) {
    int t = blockIdx.x * 256 + threadIdx.x;
    int i = t >> 4;
    int c = t & 15;
    if (i >= n) return;
    int2 ni = nodeinfo[i];
    int begin = ni.x;
    int end = ((const int*)nodeinfo)[(size_t)(i + 1) * 2];
    float di = __int_as_float(ni.y);
    float acc = __half2float(h2[(size_t)i * 16 + c]);  // self (h2 pre-scaled)
    int j = begin;
    for (; j + 4 <= end; j += 4) {
        int2 e0 = csr[j], e1 = csr[j + 1], e2 = csr[j + 2], e3 = csr[j + 3];
        float f0 = __half2float(h2[(size_t)e0.x * 16 + c]);
        float f1 = __half2float(h2[(size_t)e1.x * 16 + c]);
        float f2 = __half2float(h2[(size_t)e2.x * 16 + c]);
        float f3 = __half2float(h2[(size_t)e3.x * 16 + c]);
        acc += __int_as_float(e0.y) * f0;
        acc += __int_as_float(e1.y) * f1;
        acc += __int_as_float(e2.y) * f2;
        acc += __int_as_float(e3.y) * f3;
    }
    for (; j < end; ++j) {
        int2 e0 = csr[j];
        acc += __int_as_float(e0.y) * __half2float(h2[(size_t)e0.x * 16 + c]);
    }
    acc = di * acc + b2[c];
    float m = acc;
    for (int off = 8; off; off >>= 1) m = fmaxf(m, __shfl_xor(m, off, 16));
    float ex = expf(acc - m);
    float ssum = ex;
    for (int off = 8; off; off >>= 1) ssum += __shfl_xor(ssum, off, 16);
    out[(size_t)i * 16 + c] = ex / ssum;
}

// ---------------- launch ----------------

extern "C" void kernel_launch(void* const* d_in, const int* in_sizes, int n_in,
                              void* d_out, int out_size, void* d_ws, size_t ws_size,
                              hipStream_t stream) {
    const float* x  = (const float*)d_in[0];
    const int*   ei = (const int*)d_in[1];
    const float* ew = (const float*)d_in[2];
    const float* W1 = (const float*)d_in[3];
    const float* b1 = (const float*)d_in[4];
    const float* W2 = (const float*)d_in[5];
    const float* b2 = (const float*)d_in[6];
    float* out = (float*)d_out;

    const int N = in_sizes[0] / 128;
    const int E = in_sizes[2];
    const int* src = ei;
    const int* dst = ei + E;

    const int nbuck = (N + BNODES - 1) >> BSH;           // 196
    const int nh = nbuck * NBLK;                          // 50176
    const int nbS = (nh + SCAN_CHUNK - 1) / SCAN_CHUNK;   // 25

    char* w = (char*)d_ws;
    int2*   bucketed = (int2*)w;              w += (size_t)E * 8;
    int2*   csr      = (int2*)w;              w += (size_t)E * 8;
    __half* h1       = (__half*)w;            w += (size_t)N * 128 * 2;
    __half* h2       = (__half*)w;            w += (size_t)N * 16 * 2;
    int2*   nodeinfo = (int2*)w;              w += (size_t)(N + 1) * 8;
    int*    hist     = (int*)w;               w += (size_t)nh * 4;
    int*    bsum     = (int*)w;               w += 64 * 4;
    int*    boff     = (int*)w;               w += 64 * 4;

    int nbG_total = (N + 31) / 32;           // 3125 gemm blocks
    int nbG1 = nbG_total / 2;
    int nbG2 = nbG_total - nbG1;

    kA<<<NBLK + nbG1, 256, 0, stream>>>(dst, E, hist, nbuck, x, W1, h1, N,
                                        NBLK, nbG1, 0);
    k_scanh<<<nbS, 256, 0, stream>>>(hist, bsum, nh);
    k_scan2<<<1, 64, 0, stream>>>(bsum, boff, nbS);
    kB<<<NBLK + nbG2, 256, 0, stream>>>(src, dst, ew, E, hist, boff, nbuck,
                                        bucketed, x, W1, h1, N, NBLK, nbG2, nbG1);
    kC<<<nbuck, 256, 0, stream>>>(bucketed, hist, boff, nbuck, N, E,
                                  csr, nodeinfo, h1);
    k_agg1<<<(N + 3) / 4, 256, 0, stream>>>(h1, nodeinfo, csr, b1, W2, h2, N);
    k_agg2<<<(N + 15) / 16, 256, 0, stream>>>(h2, nodeinfo, csr, b2, out, N);
}